// Round 12
// baseline (334.066 us; speedup 1.0000x reference)
//
#include <hip/hip_runtime.h>

#define NB 8
#define LSEQ 4096
#define INS 256
#define MD 4
#define ORD 256
#define HID 512
#define MSZ 1280
#define FS 4128   // complex stride for spectrum rows (2*FS = 8256 floats)
#define NSPEC 8256
// blocked fftG geometry: [mtile 16][ntile 0..63 full + tail][mloc 128][nloc 128|64]
#define GMT 1056768   // shorts per m-tile: 64*16384 + 8192
#define GNT 16384     // shorts per full n-tile (128*128)

// padded LDS index for FFT kernels: +1 float2 per 32 (33.8 KB)
#define PD(n) ((n) + ((n) >> 5))
#define LDSN 4224

typedef __attribute__((ext_vector_type(8))) short short8;
typedef __attribute__((ext_vector_type(4))) float floatx4;

struct ush4 { unsigned short x, y, z, w; };

// Twiddle tables in code-object device memory (workspace footprint unchanged).
__device__ float2 g_tw4096[4096];   // exp(-2*pi*i*j/4096)
__device__ float2 g_tw8192[4098];   // exp(-2*pi*i*k/8192), k<=4097

__device__ __forceinline__ unsigned short f2bf(float f) {
    unsigned u = __float_as_uint(f);
    u += 0x7FFF + ((u >> 16) & 1);
    return (unsigned short)(u >> 16);
}
__device__ __forceinline__ ush4 pack4(float4 v) {
    ush4 p; p.x = f2bf(v.x); p.y = f2bf(v.y); p.z = f2bf(v.z); p.w = f2bf(v.w); return p;
}
__device__ __forceinline__ float bf2f(unsigned short s) {
    return __uint_as_float(((unsigned)s) << 16);
}

// ---------------- complex helpers (plain scalar float2 — round-6 form; inline-asm
// packed variants REGRESSED (round 8): asm blocks defeat compiler scheduling/folding) ----------------
__device__ __forceinline__ float2 cmul(float2 a, float2 b) {
    return make_float2(fmaf(a.x, b.x, -(a.y * b.y)), fmaf(a.x, b.y, a.y * b.x));
}
__device__ __forceinline__ float2 cadd(float2 a, float2 b) { return make_float2(a.x + b.x, a.y + b.y); }
__device__ __forceinline__ float2 csub(float2 a, float2 b) { return make_float2(a.x - b.x, a.y - b.y); }

template <int DIR>
__device__ __forceinline__ float2 jmul(float2 z) {
    return (DIR < 0) ? make_float2(z.y, -z.x) : make_float2(-z.y, z.x);
}

// radix-8 butterfly on 8 registers
template <int DIR>
__device__ __forceinline__ void bfly8(const float2* a, float2* b) {
    const float2 e0 = cadd(a[0], a[4]), e1 = csub(a[0], a[4]);
    const float2 e2 = cadd(a[2], a[6]), e3 = jmul<DIR>(csub(a[2], a[6]));
    const float2 E0 = cadd(e0, e2), E2 = csub(e0, e2);
    const float2 E1 = cadd(e1, e3), E3 = csub(e1, e3);
    const float2 f0 = cadd(a[1], a[5]), f1 = csub(a[1], a[5]);
    const float2 f2 = cadd(a[3], a[7]), f3 = jmul<DIR>(csub(a[3], a[7]));
    const float2 O0 = cadd(f0, f2), O2 = csub(f0, f2);
    const float2 O1 = cadd(f1, f3), O3 = csub(f1, f3);
    constexpr float C707 = 0.70710678118654752440f;
    const float2 W1 = make_float2(C707, DIR * C707);
    const float2 W3 = make_float2(-C707, DIR * C707);
    const float2 T1 = cmul(O1, W1);
    const float2 T2 = jmul<DIR>(O2);
    const float2 T3 = cmul(O3, W3);
    b[0] = cadd(E0, O0); b[4] = csub(E0, O0);
    b[1] = cadd(E1, T1); b[5] = csub(E1, T1);
    b[2] = cadd(E2, T2); b[6] = csub(E2, T2);
    b[3] = cadd(E3, T3); b[7] = csub(E3, T3);
}

// In-place Stockham DIF radix-8 stage on padded buffer. 512 threads.
// N_==8 (S_==512) specialization: p==0 for every thread -> all twiddles are unity;
// skip the 7 table loads + 7 cmuls.
template <int DIR, int N_, int S_>
__device__ __forceinline__ void fft_stage_ip(float2* __restrict__ X, int tid) {
    constexpr int M_ = N_ / 8;
    constexpr int STEP = 4096 / N_;
    const int q = tid & (S_ - 1);
    const int p = tid / S_;
    const int rb = q + S_ * p;
    float2 a[8], b[8];
#pragma unroll
    for (int l = 0; l < 8; ++l) a[l] = X[PD(rb + S_ * l * M_)];

    float2 w[7];
    if constexpr (N_ != 8) {
        const int pw = p * STEP;
#pragma unroll
        for (int j = 1; j <= 7; ++j) {
            float2 t = g_tw4096[pw * j];
            if (DIR > 0) t.y = -t.y;
            w[j - 1] = t;
        }
    }

    bfly8<DIR>(a, b);

    __syncthreads();

    const int wb = q + S_ * 8 * p;
    if constexpr (N_ == 8) {
#pragma unroll
        for (int j = 0; j < 8; ++j)
            X[PD(wb + j * S_)] = b[j];
    } else {
        X[PD(wb + 0 * S_)] = b[0];
#pragma unroll
        for (int j = 1; j < 8; ++j)
            X[PD(wb + j * S_)] = cmul(b[j], w[j - 1]);
    }
    __syncthreads();
}

// ---------------- K0: prep — weight casts + twiddle tables ----------------
extern "C" __global__ __launch_bounds__(256) void prep_k(
    const float* __restrict__ Whw, unsigned short* __restrict__ Whw_bf,
    unsigned short* __restrict__ Wt) {
    const int blk = blockIdx.x;
    if (blk < 512) {
        // Whw d-part: [512][1024] bf16, linear float4 copy of cols 0..1023
        const int idx = blk * 256 + threadIdx.x;   // 131072 float4s
        const int h = idx >> 8, c = idx & 255;
        const float4 v = ((const float4*)Whw)[(size_t)h * 320 + c];
        *(ush4*)(&Whw_bf[(size_t)idx * 4]) = pack4(v);
    } else if (blk < 640) {
        // Wt: dst linear = c*16384 + h*32 + kk ; src = Whw[h*1280 + 1024 + c*32 + kk]
        const int didx = (blk - 512) * 1024 + threadIdx.x * 4;  // 128 blocks x 1024
        const int c = didx >> 14;
        const int r = didx & 16383;
        const int h = r >> 5, kk = r & 31;
        const float4 v = *(const float4*)(Whw + (size_t)h * MSZ + 1024 + c * 32 + kk);
        *(ush4*)(&Wt[didx]) = pack4(v);
    } else if (blk < 656) {
        const int i = (blk - 640) * 256 + threadIdx.x;  // exactly 4096
        float sn, cs;
        sincosf(-1.53398078788564403e-3f * (float)i, &sn, &cs);  // -2pi/4096
        g_tw4096[i] = make_float2(cs, sn);
    } else {
        const int i = (blk - 656) * 256 + threadIdx.x;
        if (i <= 4097) {
            float sn, cs;
            sincosf(-7.66990393942820614e-4f * (float)i, &sn, &cs);  // -2pi/8192
            g_tw8192[i] = make_float2(cs, sn);
        }
    }
}

// ---------------- K1: blocks 0..255 = rfft of H rows -> fftHB bf16 (long, VALU-bound, FIRST);
// blocks 256..4351 = u_relu + x_bf cast (memory-bound; overlaps on the CUs). 512 threads. ----------------
extern "C" __global__ __launch_bounds__(512) void stage1_k(
    const float* __restrict__ x, const float* __restrict__ Wuw,
    const float* __restrict__ Wub, float* __restrict__ u_t,
    unsigned short* __restrict__ x_bf,
    const float* __restrict__ H, unsigned short* __restrict__ fftHB) {
    const int blk = blockIdx.x;
    const int tid = threadIdx.x;
    if (blk < 256) {
        __shared__ float2 A[LDSN];
        const int o = blk;
        const float2* rp = (const float2*)(H + (size_t)o * LSEQ);
        // fused stage 1 (p = tid; j>=4 zero-pad)
        {
            float2 c[8], b[8];
#pragma unroll
            for (int j = 0; j < 4; ++j) c[j] = rp[tid + j * 512];
#pragma unroll
            for (int j = 4; j < 8; ++j) c[j] = make_float2(0.f, 0.f);
            bfly8<-1>(c, b);
            A[PD(8 * tid + 0)] = b[0];
#pragma unroll
            for (int j = 1; j < 8; ++j)
                A[PD(8 * tid + j)] = cmul(b[j], g_tw4096[tid * j]);
        }
        __syncthreads();
        fft_stage_ip<-1, 512, 8>(A, tid);
        fft_stage_ip<-1, 64, 64>(A, tid);
        fft_stage_ip<-1, 8, 512>(A, tid);
        unsigned* op = (unsigned*)(fftHB + (size_t)o * NSPEC);  // pair (2k,2k+1) per 4B
#pragma unroll
        for (int j = 0; j < 9; ++j) {
            const int k = tid + j * 512;
            if (k <= 4096) {
                const float2 Zk = A[PD(k & 4095)];
                const float2 Zm = A[PD((4096 - k) & 4095)];
                const float2 E = make_float2(0.5f * (Zk.x + Zm.x), 0.5f * (Zk.y - Zm.y));
                const float2 D = make_float2(0.5f * (Zk.x - Zm.x), 0.5f * (Zk.y + Zm.y));
                const float2 O = make_float2(D.y, -D.x);
                const float2 t = g_tw8192[k];  // exp(-2*pi*i*k/8192)
                const float2 c = cadd(E, cmul(t, O));
                if (2 * k < NSPEC)
                    op[k] = (unsigned)f2bf(c.x) | ((unsigned)f2bf(c.y) << 16);
            }
        }
        return;
    }
    // ---- u_relu part: 4096 blocks x 8 rows ----
    const int row = (blk - 256) * 8 + (tid >> 6);
    const int lane = tid & 63;
    const float4 xv = ((const float4*)x)[(size_t)row * 64 + lane];
    // pack 4 bf16 into 2 dwords; even lanes store 16B covering own + odd neighbor
    unsigned d0 = (unsigned)f2bf(xv.x) | ((unsigned)f2bf(xv.y) << 16);
    unsigned d1 = (unsigned)f2bf(xv.z) | ((unsigned)f2bf(xv.w) << 16);
    const unsigned e0 = (unsigned)__shfl_xor((int)d0, 1);
    const unsigned e1 = (unsigned)__shfl_xor((int)d1, 1);
    if (!(lane & 1)) {
        uint4 v; v.x = d0; v.y = d1; v.z = e0; v.w = e1;
        *(uint4*)(&x_bf[(size_t)row * 256 + lane * 4]) = v;
    }
    const float4 w0 = ((const float4*)Wuw)[0 * 64 + lane];
    const float4 w1 = ((const float4*)Wuw)[1 * 64 + lane];
    const float4 w2 = ((const float4*)Wuw)[2 * 64 + lane];
    const float4 w3 = ((const float4*)Wuw)[3 * 64 + lane];
    float a0 = xv.x * w0.x + xv.y * w0.y + xv.z * w0.z + xv.w * w0.w;
    float a1 = xv.x * w1.x + xv.y * w1.y + xv.z * w1.z + xv.w * w1.w;
    float a2 = xv.x * w2.x + xv.y * w2.y + xv.z * w2.z + xv.w * w2.w;
    float a3 = xv.x * w3.x + xv.y * w3.y + xv.z * w3.z + xv.w * w3.w;
#pragma unroll
    for (int off = 1; off < 64; off <<= 1) {
        a0 += __shfl_xor(a0, off);
        a1 += __shfl_xor(a1, off);
        a2 += __shfl_xor(a2, off);
        a3 += __shfl_xor(a3, off);
    }
    if (lane < 4) {
        float v = (lane == 0) ? a0 : (lane == 1) ? a1 : (lane == 2) ? a2 : a3;
        v = fmaxf(v + Wub[lane], 0.0f);
        const int b = row >> 12, t = row & 4095;
        u_t[((size_t)(b * 4 + lane)) * LSEQ + t] = v;
    }
}

// ---------------- K2: blocks 0..31 = rfft of u rows -> fftU fp32 (long, FIRST);
// blocks 32..289 = ht2 transpose, 2 tiles per 512-thread block. ----------------
extern "C" __global__ __launch_bounds__(512) void stage2_k(
    const float* __restrict__ ut, float2* __restrict__ fftU,
    const unsigned short* __restrict__ fftHB, unsigned short* __restrict__ fftHT) {
    const int blk = blockIdx.x;
    const int tid = threadIdx.x;
    if (blk < 32) {
        __shared__ float2 A[LDSN];
        const float2* rp = (const float2*)(ut + (size_t)blk * LSEQ);
        {
            float2 c[8], b[8];
#pragma unroll
            for (int j = 0; j < 4; ++j) c[j] = rp[tid + j * 512];
#pragma unroll
            for (int j = 4; j < 8; ++j) c[j] = make_float2(0.f, 0.f);
            bfly8<-1>(c, b);
            A[PD(8 * tid + 0)] = b[0];
#pragma unroll
            for (int j = 1; j < 8; ++j)
                A[PD(8 * tid + j)] = cmul(b[j], g_tw4096[tid * j]);
        }
        __syncthreads();
        fft_stage_ip<-1, 512, 8>(A, tid);
        fft_stage_ip<-1, 64, 64>(A, tid);
        fft_stage_ip<-1, 8, 512>(A, tid);
        float2* op = fftU + (size_t)blk * FS;
#pragma unroll
        for (int j = 0; j < 9; ++j) {
            const int k = tid + j * 512;
            if (k <= 4096) {
                const float2 Zk = A[PD(k & 4095)];
                const float2 Zm = A[PD((4096 - k) & 4095)];
                const float2 E = make_float2(0.5f * (Zk.x + Zm.x), 0.5f * (Zk.y - Zm.y));
                const float2 D = make_float2(0.5f * (Zk.x - Zm.x), 0.5f * (Zk.y + Zm.y));
                const float2 O = make_float2(D.y, -D.x);
                const float2 t = g_tw8192[k];
                op[k] = cadd(E, cmul(t, O));
            }
        }
        return;
    }
    // ---- ht2: fftHB [256 o][8256 s] -> fftHT [8256 s][256 o], 2 tiles/block ----
    __shared__ unsigned short T[2][64 * 68];
    const int sub = tid >> 8;          // 0/1
    const int tt = tid & 255;
    const int t = (blk - 32) * 2 + sub;  // 0..515
    const int s0 = (t % 129) * 64;
    const int o0 = (t / 129) * 64;
    const int r = tt >> 4, c4 = (tt & 15) * 4;
#pragma unroll
    for (int i = 0; i < 4; ++i) {
        const int o = r + 16 * i;
        const ush4 v = *(const ush4*)(fftHB + (size_t)(o0 + o) * NSPEC + s0 + c4);
        *(ush4*)(&T[sub][o * 68 + c4]) = v;
    }
    __syncthreads();
#pragma unroll
    for (int i = 0; i < 4; ++i) {
        const int sl = r + 16 * i;
        const int s = s0 + sl;
        ush4 p;
        if (s < 8194) {
            p.x = T[sub][(c4 + 0) * 68 + sl];
            p.y = T[sub][(c4 + 1) * 68 + sl];
            p.z = T[sub][(c4 + 2) * 68 + sl];
            p.w = T[sub][(c4 + 3) * 68 + sl];
        } else { p.x = p.y = p.z = p.w = 0; }
        *(ush4*)(&fftHT[(size_t)s * 256 + o0 + c4]) = p;
    }
}

// ---------------- K4: fftG (blocked) = Whw_bf x fftHT^T via bf16 MFMA.
// Whw_bf is [512 h][1024] (d-part only). Contiguous 1024-B wave stores. ----------------
extern "C" __global__ __launch_bounds__(256) void g_gemm_k(
    const unsigned short* __restrict__ Whw_bf, const unsigned short* __restrict__ fftHT,
    unsigned short* __restrict__ fftG) {
    __shared__ __align__(16) char smem[36864];
    short* As = (short*)smem;             // [128][72]
    short* Bs = (short*)(smem + 18432);   // [128][72]
    short* Tt = (short*)smem;             // epilogue reuse: bf16 [128][136] = 34816 B

    const int tid = threadIdx.x, lane = tid & 63, wave = tid >> 6;
    // 1040 blocks = 8 XCDs * 130; within XCD: n-tile outer, m-panel (2) inner
    const int wg = blockIdx.x;
    const int loc = wg >> 3;                      // 0..129
    const int mt = (wg & 7) * 2 + (loc & 1);      // m-tile 0..15
    const int nt = loc >> 1;                      // n-tile 0..64
    const int m0 = mt * 128;
    const int n0 = nt * 128;
    floatx4 acc[2][8];
#pragma unroll
    for (int i = 0; i < 2; ++i)
#pragma unroll
        for (int j = 0; j < 8; ++j) acc[i][j] = (floatx4){0.f, 0.f, 0.f, 0.f};

    const int lr = tid >> 3;           // 0..31
    const int lc = (tid & 7) * 8;      // bf16 col: 0..56
    short8 ra[4], rb[4];

#define GL_A(kc, i) (*(const short8*)(Whw_bf + (size_t)((m0 + lr + 32 * (i)) >> 2) * 1024 + ((m0 + lr + 32 * (i)) & 3) * 256 + (kc) * 64 + lc))
#pragma unroll
    for (int i = 0; i < 4; ++i) {
        ra[i] = GL_A(0, i);
        const int n = n0 + lr + 32 * i;
        rb[i] = (n < NSPEC) ? *(const short8*)(fftHT + (size_t)n * 256 + lc)
                            : (short8){0, 0, 0, 0, 0, 0, 0, 0};
    }

    for (int kc = 0; kc < 4; ++kc) {
#pragma unroll
        for (int i = 0; i < 4; ++i) {
            *(short8*)(&As[(lr + 32 * i) * 72 + lc]) = ra[i];
            *(short8*)(&Bs[(lr + 32 * i) * 72 + lc]) = rb[i];
        }
        __syncthreads();
        if (kc < 3) {
#pragma unroll
            for (int i = 0; i < 4; ++i) {
                ra[i] = GL_A(kc + 1, i);
                const int n = n0 + lr + 32 * i;
                rb[i] = (n < NSPEC) ? *(const short8*)(fftHT + (size_t)n * 256 + (kc + 1) * 64 + lc)
                                    : (short8){0, 0, 0, 0, 0, 0, 0, 0};
            }
        }
        const int arow = (wave * 32 + (lane & 15)) * 72;
        const int brow = (lane & 15) * 72;
        const int kq = 8 * (lane >> 4);
#pragma unroll
        for (int kk = 0; kk < 2; ++kk) {
            const int ko = kk * 32 + kq;
            const short8 a0 = *(const short8*)(&As[arow + ko]);
            const short8 a1 = *(const short8*)(&As[arow + 16 * 72 + ko]);
#pragma unroll
            for (int nf = 0; nf < 8; ++nf) {
                const short8 bv = *(const short8*)(&Bs[brow + nf * 16 * 72 + ko]);
                acc[0][nf] = __builtin_amdgcn_mfma_f32_16x16x32_bf16(a0, bv, acc[0][nf], 0, 0, 0);
                acc[1][nf] = __builtin_amdgcn_mfma_f32_16x16x32_bf16(a1, bv, acc[1][nf], 0, 0, 0);
            }
        }
        __syncthreads();
    }
#undef GL_A
    // epilogue: pack to bf16 tile [128][136] in LDS, then fully-contiguous 16B stores
    const int wm = wave * 32;
#pragma unroll
    for (int mf = 0; mf < 2; ++mf) {
        const int row = wm + mf * 16 + 4 * (lane >> 4);
#pragma unroll
        for (int nf = 0; nf < 8; ++nf) {
            const int col = nf * 16 + (lane & 15);
#pragma unroll
            for (int r = 0; r < 4; ++r)
                Tt[(row + r) * 136 + col] = (short)f2bf(acc[mf][nf][r]);
        }
    }
    __syncthreads();
    const size_t gb = (size_t)mt * GMT + (size_t)nt * GNT;
    if (n0 < 8192) {
#pragma unroll
        for (int i = 0; i < 8; ++i) {
            const int idx = tid + i * 256;        // [0,2048)
            const int ml = idx >> 4, c8 = (idx & 15) * 8;
            const short8 v = *(const short8*)(&Tt[ml * 136 + c8]);
            *(short8*)(&fftG[gb + (size_t)idx * 8]) = v;
        }
    } else {
#pragma unroll
        for (int i = 0; i < 4; ++i) {
            const int idx = tid + i * 256;        // [0,1024)
            const int ml = idx >> 3, c8 = (idx & 7) * 8;
            const short8 v = *(const short8*)(&Tt[ml * 136 + c8]);
            *(short8*)(&fftG[gb + (size_t)idx * 8]) = v;
        }
    }
}

// ---------------- K5: S = sum_d fftU[b,d] * fftG[h,d]; y[b,h,:] = irfft(S)[0:4096] (bf16 out)
// Stage 1 fused into recombine; final stage fused into output (round-6 plain-float2 form). ----------------
extern "C" __global__ __launch_bounds__(512) void conv_ifft_k(
    const float2* __restrict__ fftU, const unsigned short* __restrict__ fftG,
    unsigned short* __restrict__ y) {
    __shared__ float2 A[LDSN];
    __shared__ float2 S4096;
    const int wg = blockIdx.x;  // 4096 blocks
    const int h = ((wg & 7) << 6) + (wg >> 6);  // XCD (wg&7) owns h range [x*64, x*64+64)
    const int b = (wg >> 3) & 7;
    const int tid = threadIdx.x;
    const float2* U = fftU + (size_t)b * MD * FS;
    const size_t mbase = (size_t)(h >> 5) * GMT + (size_t)((h & 31) * 4) * 128;
    const size_t tail = (size_t)(h >> 5) * GMT + (size_t)64 * GNT + (size_t)((h & 31) * 4) * 64;
#pragma unroll
    for (int j = 0; j < 9; ++j) {
        const int k = tid + j * 512;
        if (k <= 4096) {
            float2 s = make_float2(0.f, 0.f);
#pragma unroll
            for (int d = 0; d < MD; ++d) {
                const unsigned gv = (k < 4096)
                    ? *(const unsigned*)(fftG + mbase + (size_t)d * 128 + (size_t)(k >> 6) * GNT + (k & 63) * 2)
                    : *(const unsigned*)(fftG + tail + (size_t)d * 64);
                const float2 uu = U[d * FS + k];
                const float gx = __uint_as_float(gv << 16);
                const float gy = __uint_as_float(gv & 0xFFFF0000u);
                s.x = fmaf(uu.x, gx, fmaf(-uu.y, gy, s.x));
                s.y = fmaf(uu.x, gy, fmaf(uu.y, gx, s.y));
            }
            if (k < 4096) A[PD(k)] = s;
            else S4096 = s;
        }
    }
    __syncthreads();
    // recombine in registers (elements k = tid + 512j), then fused stage 1
    float2 c[8], bt[8];
#pragma unroll
    for (int j = 0; j < 8; ++j) {
        const int k = tid + j * 512;
        const float2 Sk = A[PD(k)];
        const float2 Sm = (k == 0) ? S4096 : A[PD(4096 - k)];
        const float2 E = make_float2(0.5f * (Sk.x + Sm.x), 0.5f * (Sk.y - Sm.y));
        const float2 D = make_float2(0.5f * (Sk.x - Sm.x), 0.5f * (Sk.y + Sm.y));
        const float2 t = g_tw8192[k];                    // exp(-i*2pi*k/8192)
        const float2 tc = make_float2(t.x, -t.y);        // need +angle here
        const float2 O = cmul(D, tc);
        c[j] = make_float2(E.x - O.y, E.y + O.x);
    }
    __syncthreads();   // all reads of A complete before stage-1 overwrite
    bfly8<1>(c, bt);
    A[PD(8 * tid + 0)] = bt[0];
#pragma unroll
    for (int j = 1; j < 8; ++j) {
        float2 t = g_tw4096[tid * j]; t.y = -t.y;        // conj for DIR=+1
        A[PD(8 * tid + j)] = cmul(bt[j], t);
    }
    __syncthreads();
    fft_stage_ip<1, 512, 8>(A, tid);
    fft_stage_ip<1, 64, 64>(A, tid);
    // fused final stage (p=0, twiddle-free): keep only positions < 2048
    {
        float2 z[8], bo[8];
#pragma unroll
        for (int k = 0; k < 8; ++k) z[k] = A[PD(tid + 512 * k)];
        bfly8<1>(z, bo);
        const float inv = 1.0f / 4096.0f;
#pragma unroll
        for (int k = 0; k < 4; ++k)   // same-thread same-address overwrite: no barrier needed
            A[PD(tid + 512 * k)] = make_float2(bo[k].x * inv, bo[k].y * inv);
    }
    __syncthreads();
    unsigned short* yp = y + (size_t)(b * HID + h) * LSEQ;
    {
        const int q = tid;  // 512 threads x 16B = full 8192-B row
        unsigned dw[4];
#pragma unroll
        for (int jj = 0; jj < 4; ++jj) {
            const float2 z = A[PD(4 * q + jj)];
            dw[jj] = (unsigned)f2bf(z.x) | ((unsigned)f2bf(z.y) << 16);
        }
        uint4 v; v.x = dw[0]; v.y = dw[1]; v.z = dw[2]; v.w = dw[3];
        *(uint4*)(yp + 8 * q) = v;
    }
}

// ---------------- K6: h = relu(x @ Whw_x^T + y^T + bias); 32m x 512h blocks, row-contiguous
// wave stores. LDS 66.5 -> 39.2 KB (staging pad 36 + Ct split into two mf-half passes,
// each matching the acc[mf] register split so ALL waves work in both passes) -> 4 blocks/CU. ----------------
extern "C" __global__ __launch_bounds__(256) void out_gemm_k(
    const unsigned short* __restrict__ x_bf, const unsigned short* __restrict__ Wt,
    const float* __restrict__ Whb, const unsigned short* __restrict__ y,
    float* __restrict__ out) {
    __shared__ __align__(16) char smem[39168];
    short* As = (short*)smem;              // [32][36] shorts = 2304 B
    short* Bs = (short*)(smem + 2304);     // [512][36] shorts = 36864 B
    float* Whbs = (float*)smem;            // epilogue: 512 floats = 2048 B (aliases dead As)
    short* Ys = (short*)(smem + 2304);     // epilogue: bf16 [512][36] (aliases dead Bs)
    float* Ct = (float*)smem;              // epilogue pass: [16][520] floats = 33280 B

    const int tid = threadIdx.x, lane = tid & 63, wave = tid >> 6;
    const int wg = blockIdx.x;
    const int s = ((wg & 7) << 7) + (wg >> 3);
    const int m0 = s * 32;
    const int b = m0 >> 12;          // == wg & 7
    const int t0 = m0 & 4095;
    const int hq = wave * 128;       // wave's h-quarter

    floatx4 acc[2][8];
#pragma unroll
    for (int i = 0; i < 2; ++i)
#pragma unroll
        for (int j = 0; j < 8; ++j) acc[i][j] = (floatx4){0.f, 0.f, 0.f, 0.f};

    short8 ra, rb[8];
    const int arow = tid >> 2, acb = (tid & 3) * 8;
    if (tid < 128) ra = *(const short8*)(x_bf + (size_t)(m0 + arow) * INS + acb);
#pragma unroll
    for (int j = 0; j < 8; ++j)
        rb[j] = *(const short8*)(Wt + (size_t)tid * 64 + j * 8);

    for (int c = 0; c < 8; ++c) {
        if (tid < 128) *(short8*)(&As[arow * 36 + acb]) = ra;
#pragma unroll
        for (int j = 0; j < 8; ++j)
            *(short8*)(&Bs[(2 * tid + (j >> 2)) * 36 + (j & 3) * 8]) = rb[j];
        __syncthreads();
        if (c < 7) {
            if (tid < 128) ra = *(const short8*)(x_bf + (size_t)(m0 + arow) * INS + (c + 1) * 32 + acb);
#pragma unroll
            for (int j = 0; j < 8; ++j)
                rb[j] = *(const short8*)(Wt + (size_t)(c + 1) * 16384 + (size_t)tid * 64 + j * 8);
        }
        const int kq = 8 * (lane >> 4);
        const short8 a0 = *(const short8*)(&As[(lane & 15) * 36 + kq]);
        const short8 a1 = *(const short8*)(&As[((lane & 15) + 16) * 36 + kq]);
#pragma unroll
        for (int nf = 0; nf < 8; ++nf) {
            const short8 bv = *(const short8*)(&Bs[(hq + nf * 16 + (lane & 15)) * 36 + kq]);
            acc[0][nf] = __builtin_amdgcn_mfma_f32_16x16x32_bf16(a0, bv, acc[0][nf], 0, 0, 0);
            acc[1][nf] = __builtin_amdgcn_mfma_f32_16x16x32_bf16(a1, bv, acc[1][nf], 0, 0, 0);
        }
        __syncthreads();
    }

    // epilogue: stage bias + y^T (bf16) in LDS (round-5 proven pattern, pad 36), relu into acc
    Whbs[tid] = Whb[tid];
    Whbs[tid + 256] = Whb[tid + 256];
#pragma unroll
    for (int i = 0; i < 16; ++i) {
        const int idx = tid + i * 256;          // 0..4095
        const int hh = idx >> 3, tq = (idx & 7) * 4;
        const ush4 v = *(const ush4*)(y + (size_t)(b * HID + hh) * LSEQ + t0 + tq);
        *(ush4*)(&Ys[hh * 36 + tq]) = v;
    }
    __syncthreads();
#pragma unroll
    for (int nf = 0; nf < 8; ++nf) {
        const int hh = hq + nf * 16 + (lane & 15);
        const float bias = Whbs[hh];
#pragma unroll
        for (int mf = 0; mf < 2; ++mf)
#pragma unroll
            for (int r = 0; r < 4; ++r) {
                const int row = mf * 16 + 4 * (lane >> 4) + r;
                acc[mf][nf][r] = fmaxf(acc[mf][nf][r] + bf2f(Ys[hh * 36 + row]) + bias, 0.f);
            }
    }
    // transpose + store per mf-half: Ct [16][520] = 33.3 KB, all waves active both passes
#pragma unroll 1
    for (int mf = 0; mf < 2; ++mf) {
        __syncthreads();   // prior Ys/Whbs (or previous Ct) reads complete before overwrite
#pragma unroll
        for (int nf = 0; nf < 8; ++nf) {
            const int col = hq + nf * 16 + (lane & 15);
#pragma unroll
            for (int r = 0; r < 4; ++r) {
                const int row = 4 * (lane >> 4) + r;     // 0..15
                Ct[row * 520 + col] = acc[mf][nf][r];
            }
        }
        __syncthreads();
#pragma unroll
        for (int i = 0; i < 8; ++i) {
            const int idx = tid + i * 256;               // 0..2047 float4s
            const int row = idx >> 7, c4 = (idx & 127) * 4;
            const floatx4 t = *(const floatx4*)&Ct[row * 520 + c4];
            const int mrow = m0 + mf * 16 + row;
            *(floatx4*)(out + (size_t)mrow * HID + c4) = t;
            if ((mrow & 4095) == 4095)
                *(floatx4*)(out + (size_t)NB * LSEQ * HID + (size_t)b * HID + c4) = t;
        }
    }
}

extern "C" void kernel_launch(void* const* d_in, const int* in_sizes, int n_in,
                              void* d_out, int out_size, void* d_ws, size_t ws_size,
                              hipStream_t stream) {
    const float* x   = (const float*)d_in[0];
    const float* Wuw = (const float*)d_in[1];
    const float* Wub = (const float*)d_in[2];
    const float* Whw = (const float*)d_in[3];
    const float* Whb = (const float*)d_in[4];
    const float* H   = (const float*)d_in[5];
    char* wsb = (char*)d_ws;
    // workspace layout — byte-identical footprint to the verified round-1 layout
    unsigned short* fftG   = (unsigned short*)(wsb);             // blocked, 33,816,576 B
    unsigned short* yb     = (unsigned short*)(wsb + 33816576);  // 8*512*4096 bf16  = 33,554,432
    float2*         fftU   = (float2*)(wsb + 67371008);          // 32*4128 float2   =  1,056,768
    unsigned short* fftHT  = (unsigned short*)(wsb + 68427776);  // 8256*256 bf16    =  4,227,072
    float*          ut     = (float*)(wsb + 72654848);           // 32*4096 fp32     =    524,288
    unsigned short* x_bf   = (unsigned short*)(wsb + 73179136);  // 32768*256 bf16   = 16,777,216
    unsigned short* Whw_bf = (unsigned short*)(wsb + 89956352);  // [512][1024] bf16 =  1,048,576
    unsigned short* Wt     = (unsigned short*)(wsb + 91004928);  // [8][512][32] bf16=    262,144
    unsigned short* fftHB  = (unsigned short*)(wsb + 91267072);  // 256*8256 bf16    =  4,227,072
    float* out = (float*)d_out;

    hipLaunchKernelGGL(prep_k, dim3(673), dim3(256), 0, stream, Whw, Whw_bf, Wt);
    hipLaunchKernelGGL(stage1_k, dim3(4352), dim3(512), 0, stream, x, Wuw, Wub, ut, x_bf, H, fftHB);
    hipLaunchKernelGGL(stage2_k, dim3(290), dim3(512), 0, stream, ut, fftU, fftHB, fftHT);
    hipLaunchKernelGGL(g_gemm_k, dim3(1040), dim3(256), 0, stream, Whw_bf, fftHT, fftG);
    hipLaunchKernelGGL(conv_ifft_k, dim3(4096), dim3(512), 0, stream, fftU, fftG, yb);
    hipLaunchKernelGGL(out_gemm_k, dim3(1024), dim3(256), 0, stream, x_bf, Wt, Whb, yb, out);
}

// Round 13
// 246.557 us; speedup vs baseline: 1.3549x; 1.3549x over previous
//
#include <hip/hip_runtime.h>

#define NB 8
#define LSEQ 4096
#define INS 256
#define MD 4
#define ORD 256
#define HID 512
#define MSZ 1280
#define FS 4128   // complex stride for spectrum rows (2*FS = 8256 floats)
#define NSPEC 8256
// blocked fftG geometry: [mtile 16][ntile 0..63 full + tail][mloc 128][nloc 128|64]
#define GMT 1056768   // shorts per m-tile: 64*16384 + 8192
#define GNT 16384     // shorts per full n-tile (128*128)

// padded LDS index for FFT kernels: +1 float2 per 32 (33.8 KB)
#define PD(n) ((n) + ((n) >> 5))
#define LDSN 4224

typedef __attribute__((ext_vector_type(8))) short short8;
typedef __attribute__((ext_vector_type(4))) float floatx4;

struct ush4 { unsigned short x, y, z, w; };

// Twiddle tables in code-object device memory (workspace footprint unchanged).
__device__ float2 g_tw4096[4096];   // exp(-2*pi*i*j/4096)
__device__ float2 g_tw8192[4098];   // exp(-2*pi*i*k/8192), k<=4097

__device__ __forceinline__ unsigned short f2bf(float f) {
    unsigned u = __float_as_uint(f);
    u += 0x7FFF + ((u >> 16) & 1);
    return (unsigned short)(u >> 16);
}
__device__ __forceinline__ ush4 pack4(float4 v) {
    ush4 p; p.x = f2bf(v.x); p.y = f2bf(v.y); p.z = f2bf(v.z); p.w = f2bf(v.w); return p;
}
__device__ __forceinline__ float bf2f(unsigned short s) {
    return __uint_as_float(((unsigned)s) << 16);
}

// ---------------- complex helpers (plain scalar float2 — round-6 form; inline-asm
// packed variants REGRESSED (round 8): asm blocks defeat compiler scheduling/folding) ----------------
__device__ __forceinline__ float2 cmul(float2 a, float2 b) {
    return make_float2(fmaf(a.x, b.x, -(a.y * b.y)), fmaf(a.x, b.y, a.y * b.x));
}
__device__ __forceinline__ float2 cadd(float2 a, float2 b) { return make_float2(a.x + b.x, a.y + b.y); }
__device__ __forceinline__ float2 csub(float2 a, float2 b) { return make_float2(a.x - b.x, a.y - b.y); }

template <int DIR>
__device__ __forceinline__ float2 jmul(float2 z) {
    return (DIR < 0) ? make_float2(z.y, -z.x) : make_float2(-z.y, z.x);
}

// radix-8 butterfly on 8 registers
template <int DIR>
__device__ __forceinline__ void bfly8(const float2* a, float2* b) {
    const float2 e0 = cadd(a[0], a[4]), e1 = csub(a[0], a[4]);
    const float2 e2 = cadd(a[2], a[6]), e3 = jmul<DIR>(csub(a[2], a[6]));
    const float2 E0 = cadd(e0, e2), E2 = csub(e0, e2);
    const float2 E1 = cadd(e1, e3), E3 = csub(e1, e3);
    const float2 f0 = cadd(a[1], a[5]), f1 = csub(a[1], a[5]);
    const float2 f2 = cadd(a[3], a[7]), f3 = jmul<DIR>(csub(a[3], a[7]));
    const float2 O0 = cadd(f0, f2), O2 = csub(f0, f2);
    const float2 O1 = cadd(f1, f3), O3 = csub(f1, f3);
    constexpr float C707 = 0.70710678118654752440f;
    const float2 W1 = make_float2(C707, DIR * C707);
    const float2 W3 = make_float2(-C707, DIR * C707);
    const float2 T1 = cmul(O1, W1);
    const float2 T2 = jmul<DIR>(O2);
    const float2 T3 = cmul(O3, W3);
    b[0] = cadd(E0, O0); b[4] = csub(E0, O0);
    b[1] = cadd(E1, T1); b[5] = csub(E1, T1);
    b[2] = cadd(E2, T2); b[6] = csub(E2, T2);
    b[3] = cadd(E3, T3); b[7] = csub(E3, T3);
}

// In-place Stockham DIF radix-8 stage on padded buffer. 512 threads.
// N_==8 (S_==512) specialization: p==0 for every thread -> all twiddles are unity;
// skip the 7 table loads + 7 cmuls.
template <int DIR, int N_, int S_>
__device__ __forceinline__ void fft_stage_ip(float2* __restrict__ X, int tid) {
    constexpr int M_ = N_ / 8;
    constexpr int STEP = 4096 / N_;
    const int q = tid & (S_ - 1);
    const int p = tid / S_;
    const int rb = q + S_ * p;
    float2 a[8], b[8];
#pragma unroll
    for (int l = 0; l < 8; ++l) a[l] = X[PD(rb + S_ * l * M_)];

    float2 w[7];
    if constexpr (N_ != 8) {
        const int pw = p * STEP;
#pragma unroll
        for (int j = 1; j <= 7; ++j) {
            float2 t = g_tw4096[pw * j];
            if (DIR > 0) t.y = -t.y;
            w[j - 1] = t;
        }
    }

    bfly8<DIR>(a, b);

    __syncthreads();

    const int wb = q + S_ * 8 * p;
    if constexpr (N_ == 8) {
#pragma unroll
        for (int j = 0; j < 8; ++j)
            X[PD(wb + j * S_)] = b[j];
    } else {
        X[PD(wb + 0 * S_)] = b[0];
#pragma unroll
        for (int j = 1; j < 8; ++j)
            X[PD(wb + j * S_)] = cmul(b[j], w[j - 1]);
    }
    __syncthreads();
}

// ---------------- K0: prep — weight casts + twiddle tables ----------------
extern "C" __global__ __launch_bounds__(256) void prep_k(
    const float* __restrict__ Whw, unsigned short* __restrict__ Whw_bf,
    unsigned short* __restrict__ Wt) {
    const int blk = blockIdx.x;
    if (blk < 512) {
        // Whw d-part: [512][1024] bf16, linear float4 copy of cols 0..1023
        const int idx = blk * 256 + threadIdx.x;   // 131072 float4s
        const int h = idx >> 8, c = idx & 255;
        const float4 v = ((const float4*)Whw)[(size_t)h * 320 + c];
        *(ush4*)(&Whw_bf[(size_t)idx * 4]) = pack4(v);
    } else if (blk < 640) {
        // Wt: dst linear = c*16384 + h*32 + kk ; src = Whw[h*1280 + 1024 + c*32 + kk]
        const int didx = (blk - 512) * 1024 + threadIdx.x * 4;  // 128 blocks x 1024
        const int c = didx >> 14;
        const int r = didx & 16383;
        const int h = r >> 5, kk = r & 31;
        const float4 v = *(const float4*)(Whw + (size_t)h * MSZ + 1024 + c * 32 + kk);
        *(ush4*)(&Wt[didx]) = pack4(v);
    } else if (blk < 656) {
        const int i = (blk - 640) * 256 + threadIdx.x;  // exactly 4096
        float sn, cs;
        sincosf(-1.53398078788564403e-3f * (float)i, &sn, &cs);  // -2pi/4096
        g_tw4096[i] = make_float2(cs, sn);
    } else {
        const int i = (blk - 656) * 256 + threadIdx.x;
        if (i <= 4097) {
            float sn, cs;
            sincosf(-7.66990393942820614e-4f * (float)i, &sn, &cs);  // -2pi/8192
            g_tw8192[i] = make_float2(cs, sn);
        }
    }
}

// ---------------- K1: blocks 0..255 = rfft of H rows -> fftHB bf16 (long, VALU-bound, FIRST);
// blocks 256..4351 = u_relu + x_bf cast (memory-bound; overlaps on the CUs). 512 threads. ----------------
extern "C" __global__ __launch_bounds__(512) void stage1_k(
    const float* __restrict__ x, const float* __restrict__ Wuw,
    const float* __restrict__ Wub, float* __restrict__ u_t,
    unsigned short* __restrict__ x_bf,
    const float* __restrict__ H, unsigned short* __restrict__ fftHB) {
    const int blk = blockIdx.x;
    const int tid = threadIdx.x;
    if (blk < 256) {
        __shared__ float2 A[LDSN];
        const int o = blk;
        const float2* rp = (const float2*)(H + (size_t)o * LSEQ);
        // fused stage 1 (p = tid; j>=4 zero-pad)
        {
            float2 c[8], b[8];
#pragma unroll
            for (int j = 0; j < 4; ++j) c[j] = rp[tid + j * 512];
#pragma unroll
            for (int j = 4; j < 8; ++j) c[j] = make_float2(0.f, 0.f);
            bfly8<-1>(c, b);
            A[PD(8 * tid + 0)] = b[0];
#pragma unroll
            for (int j = 1; j < 8; ++j)
                A[PD(8 * tid + j)] = cmul(b[j], g_tw4096[tid * j]);
        }
        __syncthreads();
        fft_stage_ip<-1, 512, 8>(A, tid);
        fft_stage_ip<-1, 64, 64>(A, tid);
        fft_stage_ip<-1, 8, 512>(A, tid);
        unsigned* op = (unsigned*)(fftHB + (size_t)o * NSPEC);  // pair (2k,2k+1) per 4B
#pragma unroll
        for (int j = 0; j < 9; ++j) {
            const int k = tid + j * 512;
            if (k <= 4096) {
                const float2 Zk = A[PD(k & 4095)];
                const float2 Zm = A[PD((4096 - k) & 4095)];
                const float2 E = make_float2(0.5f * (Zk.x + Zm.x), 0.5f * (Zk.y - Zm.y));
                const float2 D = make_float2(0.5f * (Zk.x - Zm.x), 0.5f * (Zk.y + Zm.y));
                const float2 O = make_float2(D.y, -D.x);
                const float2 t = g_tw8192[k];  // exp(-2*pi*i*k/8192)
                const float2 c = cadd(E, cmul(t, O));
                if (2 * k < NSPEC)
                    op[k] = (unsigned)f2bf(c.x) | ((unsigned)f2bf(c.y) << 16);
            }
        }
        return;
    }
    // ---- u_relu part: 4096 blocks x 8 rows ----
    const int row = (blk - 256) * 8 + (tid >> 6);
    const int lane = tid & 63;
    const float4 xv = ((const float4*)x)[(size_t)row * 64 + lane];
    // pack 4 bf16 into 2 dwords; even lanes store 16B covering own + odd neighbor
    unsigned d0 = (unsigned)f2bf(xv.x) | ((unsigned)f2bf(xv.y) << 16);
    unsigned d1 = (unsigned)f2bf(xv.z) | ((unsigned)f2bf(xv.w) << 16);
    const unsigned e0 = (unsigned)__shfl_xor((int)d0, 1);
    const unsigned e1 = (unsigned)__shfl_xor((int)d1, 1);
    if (!(lane & 1)) {
        uint4 v; v.x = d0; v.y = d1; v.z = e0; v.w = e1;
        *(uint4*)(&x_bf[(size_t)row * 256 + lane * 4]) = v;
    }
    const float4 w0 = ((const float4*)Wuw)[0 * 64 + lane];
    const float4 w1 = ((const float4*)Wuw)[1 * 64 + lane];
    const float4 w2 = ((const float4*)Wuw)[2 * 64 + lane];
    const float4 w3 = ((const float4*)Wuw)[3 * 64 + lane];
    float a0 = xv.x * w0.x + xv.y * w0.y + xv.z * w0.z + xv.w * w0.w;
    float a1 = xv.x * w1.x + xv.y * w1.y + xv.z * w1.z + xv.w * w1.w;
    float a2 = xv.x * w2.x + xv.y * w2.y + xv.z * w2.z + xv.w * w2.w;
    float a3 = xv.x * w3.x + xv.y * w3.y + xv.z * w3.z + xv.w * w3.w;
#pragma unroll
    for (int off = 1; off < 64; off <<= 1) {
        a0 += __shfl_xor(a0, off);
        a1 += __shfl_xor(a1, off);
        a2 += __shfl_xor(a2, off);
        a3 += __shfl_xor(a3, off);
    }
    if (lane < 4) {
        float v = (lane == 0) ? a0 : (lane == 1) ? a1 : (lane == 2) ? a2 : a3;
        v = fmaxf(v + Wub[lane], 0.0f);
        const int b = row >> 12, t = row & 4095;
        u_t[((size_t)(b * 4 + lane)) * LSEQ + t] = v;
    }
}

// ---------------- K2: blocks 0..31 = rfft of u rows -> fftU fp32 (long, FIRST);
// blocks 32..289 = ht2 transpose, 2 tiles per 512-thread block. ----------------
extern "C" __global__ __launch_bounds__(512) void stage2_k(
    const float* __restrict__ ut, float2* __restrict__ fftU,
    const unsigned short* __restrict__ fftHB, unsigned short* __restrict__ fftHT) {
    const int blk = blockIdx.x;
    const int tid = threadIdx.x;
    if (blk < 32) {
        __shared__ float2 A[LDSN];
        const float2* rp = (const float2*)(ut + (size_t)blk * LSEQ);
        {
            float2 c[8], b[8];
#pragma unroll
            for (int j = 0; j < 4; ++j) c[j] = rp[tid + j * 512];
#pragma unroll
            for (int j = 4; j < 8; ++j) c[j] = make_float2(0.f, 0.f);
            bfly8<-1>(c, b);
            A[PD(8 * tid + 0)] = b[0];
#pragma unroll
            for (int j = 1; j < 8; ++j)
                A[PD(8 * tid + j)] = cmul(b[j], g_tw4096[tid * j]);
        }
        __syncthreads();
        fft_stage_ip<-1, 512, 8>(A, tid);
        fft_stage_ip<-1, 64, 64>(A, tid);
        fft_stage_ip<-1, 8, 512>(A, tid);
        float2* op = fftU + (size_t)blk * FS;
#pragma unroll
        for (int j = 0; j < 9; ++j) {
            const int k = tid + j * 512;
            if (k <= 4096) {
                const float2 Zk = A[PD(k & 4095)];
                const float2 Zm = A[PD((4096 - k) & 4095)];
                const float2 E = make_float2(0.5f * (Zk.x + Zm.x), 0.5f * (Zk.y - Zm.y));
                const float2 D = make_float2(0.5f * (Zk.x - Zm.x), 0.5f * (Zk.y + Zm.y));
                const float2 O = make_float2(D.y, -D.x);
                const float2 t = g_tw8192[k];
                op[k] = cadd(E, cmul(t, O));
            }
        }
        return;
    }
    // ---- ht2: fftHB [256 o][8256 s] -> fftHT [8256 s][256 o], 2 tiles/block ----
    __shared__ unsigned short T[2][64 * 68];
    const int sub = tid >> 8;          // 0/1
    const int tt = tid & 255;
    const int t = (blk - 32) * 2 + sub;  // 0..515
    const int s0 = (t % 129) * 64;
    const int o0 = (t / 129) * 64;
    const int r = tt >> 4, c4 = (tt & 15) * 4;
#pragma unroll
    for (int i = 0; i < 4; ++i) {
        const int o = r + 16 * i;
        const ush4 v = *(const ush4*)(fftHB + (size_t)(o0 + o) * NSPEC + s0 + c4);
        *(ush4*)(&T[sub][o * 68 + c4]) = v;
    }
    __syncthreads();
#pragma unroll
    for (int i = 0; i < 4; ++i) {
        const int sl = r + 16 * i;
        const int s = s0 + sl;
        ush4 p;
        if (s < 8194) {
            p.x = T[sub][(c4 + 0) * 68 + sl];
            p.y = T[sub][(c4 + 1) * 68 + sl];
            p.z = T[sub][(c4 + 2) * 68 + sl];
            p.w = T[sub][(c4 + 3) * 68 + sl];
        } else { p.x = p.y = p.z = p.w = 0; }
        *(ush4*)(&fftHT[(size_t)s * 256 + o0 + c4]) = p;
    }
}

// ---------------- K4: fftG (blocked) = Whw_bf x fftHT^T via bf16 MFMA.
// Whw_bf is [512 h][1024] (d-part only). Contiguous 1024-B wave stores. ----------------
extern "C" __global__ __launch_bounds__(256) void g_gemm_k(
    const unsigned short* __restrict__ Whw_bf, const unsigned short* __restrict__ fftHT,
    unsigned short* __restrict__ fftG) {
    __shared__ __align__(16) char smem[36864];
    short* As = (short*)smem;             // [128][72]
    short* Bs = (short*)(smem + 18432);   // [128][72]
    short* Tt = (short*)smem;             // epilogue reuse: bf16 [128][136] = 34816 B

    const int tid = threadIdx.x, lane = tid & 63, wave = tid >> 6;
    // 1040 blocks = 8 XCDs * 130; within XCD: n-tile outer, m-panel (2) inner
    const int wg = blockIdx.x;
    const int loc = wg >> 3;                      // 0..129
    const int mt = (wg & 7) * 2 + (loc & 1);      // m-tile 0..15
    const int nt = loc >> 1;                      // n-tile 0..64
    const int m0 = mt * 128;
    const int n0 = nt * 128;
    floatx4 acc[2][8];
#pragma unroll
    for (int i = 0; i < 2; ++i)
#pragma unroll
        for (int j = 0; j < 8; ++j) acc[i][j] = (floatx4){0.f, 0.f, 0.f, 0.f};

    const int lr = tid >> 3;           // 0..31
    const int lc = (tid & 7) * 8;      // bf16 col: 0..56
    short8 ra[4], rb[4];

#define GL_A(kc, i) (*(const short8*)(Whw_bf + (size_t)((m0 + lr + 32 * (i)) >> 2) * 1024 + ((m0 + lr + 32 * (i)) & 3) * 256 + (kc) * 64 + lc))
#pragma unroll
    for (int i = 0; i < 4; ++i) {
        ra[i] = GL_A(0, i);
        const int n = n0 + lr + 32 * i;
        rb[i] = (n < NSPEC) ? *(const short8*)(fftHT + (size_t)n * 256 + lc)
                            : (short8){0, 0, 0, 0, 0, 0, 0, 0};
    }

    for (int kc = 0; kc < 4; ++kc) {
#pragma unroll
        for (int i = 0; i < 4; ++i) {
            *(short8*)(&As[(lr + 32 * i) * 72 + lc]) = ra[i];
            *(short8*)(&Bs[(lr + 32 * i) * 72 + lc]) = rb[i];
        }
        __syncthreads();
        if (kc < 3) {
#pragma unroll
            for (int i = 0; i < 4; ++i) {
                ra[i] = GL_A(kc + 1, i);
                const int n = n0 + lr + 32 * i;
                rb[i] = (n < NSPEC) ? *(const short8*)(fftHT + (size_t)n * 256 + (kc + 1) * 64 + lc)
                                    : (short8){0, 0, 0, 0, 0, 0, 0, 0};
            }
        }
        const int arow = (wave * 32 + (lane & 15)) * 72;
        const int brow = (lane & 15) * 72;
        const int kq = 8 * (lane >> 4);
#pragma unroll
        for (int kk = 0; kk < 2; ++kk) {
            const int ko = kk * 32 + kq;
            const short8 a0 = *(const short8*)(&As[arow + ko]);
            const short8 a1 = *(const short8*)(&As[arow + 16 * 72 + ko]);
#pragma unroll
            for (int nf = 0; nf < 8; ++nf) {
                const short8 bv = *(const short8*)(&Bs[brow + nf * 16 * 72 + ko]);
                acc[0][nf] = __builtin_amdgcn_mfma_f32_16x16x32_bf16(a0, bv, acc[0][nf], 0, 0, 0);
                acc[1][nf] = __builtin_amdgcn_mfma_f32_16x16x32_bf16(a1, bv, acc[1][nf], 0, 0, 0);
            }
        }
        __syncthreads();
    }
#undef GL_A
    // epilogue: pack to bf16 tile [128][136] in LDS, then fully-contiguous 16B stores
    const int wm = wave * 32;
#pragma unroll
    for (int mf = 0; mf < 2; ++mf) {
        const int row = wm + mf * 16 + 4 * (lane >> 4);
#pragma unroll
        for (int nf = 0; nf < 8; ++nf) {
            const int col = nf * 16 + (lane & 15);
#pragma unroll
            for (int r = 0; r < 4; ++r)
                Tt[(row + r) * 136 + col] = (short)f2bf(acc[mf][nf][r]);
        }
    }
    __syncthreads();
    const size_t gb = (size_t)mt * GMT + (size_t)nt * GNT;
    if (n0 < 8192) {
#pragma unroll
        for (int i = 0; i < 8; ++i) {
            const int idx = tid + i * 256;        // [0,2048)
            const int ml = idx >> 4, c8 = (idx & 15) * 8;
            const short8 v = *(const short8*)(&Tt[ml * 136 + c8]);
            *(short8*)(&fftG[gb + (size_t)idx * 8]) = v;
        }
    } else {
#pragma unroll
        for (int i = 0; i < 4; ++i) {
            const int idx = tid + i * 256;        // [0,1024)
            const int ml = idx >> 3, c8 = (idx & 7) * 8;
            const short8 v = *(const short8*)(&Tt[ml * 136 + c8]);
            *(short8*)(&fftG[gb + (size_t)idx * 8]) = v;
        }
    }
}

// ---------------- K5: S = sum_d fftU[b,d] * fftG[h,d]; y[b,h,:] = irfft(S)[0:4096] (bf16 out)
// Stage 1 fused into recombine; final stage fused into output (round-6 plain-float2 form). ----------------
extern "C" __global__ __launch_bounds__(512) void conv_ifft_k(
    const float2* __restrict__ fftU, const unsigned short* __restrict__ fftG,
    unsigned short* __restrict__ y) {
    __shared__ float2 A[LDSN];
    __shared__ float2 S4096;
    const int wg = blockIdx.x;  // 4096 blocks
    const int h = ((wg & 7) << 6) + (wg >> 6);  // XCD (wg&7) owns h range [x*64, x*64+64)
    const int b = (wg >> 3) & 7;
    const int tid = threadIdx.x;
    const float2* U = fftU + (size_t)b * MD * FS;
    const size_t mbase = (size_t)(h >> 5) * GMT + (size_t)((h & 31) * 4) * 128;
    const size_t tail = (size_t)(h >> 5) * GMT + (size_t)64 * GNT + (size_t)((h & 31) * 4) * 64;
#pragma unroll
    for (int j = 0; j < 9; ++j) {
        const int k = tid + j * 512;
        if (k <= 4096) {
            float2 s = make_float2(0.f, 0.f);
#pragma unroll
            for (int d = 0; d < MD; ++d) {
                const unsigned gv = (k < 4096)
                    ? *(const unsigned*)(fftG + mbase + (size_t)d * 128 + (size_t)(k >> 6) * GNT + (k & 63) * 2)
                    : *(const unsigned*)(fftG + tail + (size_t)d * 64);
                const float2 uu = U[d * FS + k];
                const float gx = __uint_as_float(gv << 16);
                const float gy = __uint_as_float(gv & 0xFFFF0000u);
                s.x = fmaf(uu.x, gx, fmaf(-uu.y, gy, s.x));
                s.y = fmaf(uu.x, gy, fmaf(uu.y, gx, s.y));
            }
            if (k < 4096) A[PD(k)] = s;
            else S4096 = s;
        }
    }
    __syncthreads();
    // recombine in registers (elements k = tid + 512j), then fused stage 1
    float2 c[8], bt[8];
#pragma unroll
    for (int j = 0; j < 8; ++j) {
        const int k = tid + j * 512;
        const float2 Sk = A[PD(k)];
        const float2 Sm = (k == 0) ? S4096 : A[PD(4096 - k)];
        const float2 E = make_float2(0.5f * (Sk.x + Sm.x), 0.5f * (Sk.y - Sm.y));
        const float2 D = make_float2(0.5f * (Sk.x - Sm.x), 0.5f * (Sk.y + Sm.y));
        const float2 t = g_tw8192[k];                    // exp(-i*2pi*k/8192)
        const float2 tc = make_float2(t.x, -t.y);        // need +angle here
        const float2 O = cmul(D, tc);
        c[j] = make_float2(E.x - O.y, E.y + O.x);
    }
    __syncthreads();   // all reads of A complete before stage-1 overwrite
    bfly8<1>(c, bt);
    A[PD(8 * tid + 0)] = bt[0];
#pragma unroll
    for (int j = 1; j < 8; ++j) {
        float2 t = g_tw4096[tid * j]; t.y = -t.y;        // conj for DIR=+1
        A[PD(8 * tid + j)] = cmul(bt[j], t);
    }
    __syncthreads();
    fft_stage_ip<1, 512, 8>(A, tid);
    fft_stage_ip<1, 64, 64>(A, tid);
    // fused final stage (p=0, twiddle-free): keep only positions < 2048
    {
        float2 z[8], bo[8];
#pragma unroll
        for (int k = 0; k < 8; ++k) z[k] = A[PD(tid + 512 * k)];
        bfly8<1>(z, bo);
        const float inv = 1.0f / 4096.0f;
#pragma unroll
        for (int k = 0; k < 4; ++k)   // same-thread same-address overwrite: no barrier needed
            A[PD(tid + 512 * k)] = make_float2(bo[k].x * inv, bo[k].y * inv);
    }
    __syncthreads();
    unsigned short* yp = y + (size_t)(b * HID + h) * LSEQ;
    {
        const int q = tid;  // 512 threads x 16B = full 8192-B row
        unsigned dw[4];
#pragma unroll
        for (int jj = 0; jj < 4; ++jj) {
            const float2 z = A[PD(4 * q + jj)];
            dw[jj] = (unsigned)f2bf(z.x) | ((unsigned)f2bf(z.y) << 16);
        }
        uint4 v; v.x = dw[0]; v.y = dw[1]; v.z = dw[2]; v.w = dw[3];
        *(uint4*)(yp + 8 * q) = v;
    }
}

// ---------------- K6: h = relu(x @ Whw_x^T + y^T + bias); 32m x 512h blocks so every
// wave store is a single contiguous 1024-B segment within one out row.
// REVERTED to round-5/round-11 form: 66.5 KB LDS / 2 blocks/CU. Both occupancy-raising
// variants (r6: +20us, r12: +73us, WRITE 683MB) regressed — 4 blocks/CU causes ~10x HBM
// write amplification despite fully-contiguous region writes. 2 blocks/CU is the optimum. ----------------
extern "C" __global__ __launch_bounds__(256) void out_gemm_k(
    const unsigned short* __restrict__ x_bf, const unsigned short* __restrict__ Wt,
    const float* __restrict__ Whb, const unsigned short* __restrict__ y,
    float* __restrict__ out) {
    __shared__ __align__(16) char smem[66560];
    short* As = (short*)smem;              // [32][40] shorts = 2560 B
    short* Bs = (short*)(smem + 2560);     // [512][40] shorts = 40960 B
    float* Whbs = (float*)smem;            // epilogue: 512 floats (aliases dead As)
    short* Ys = (short*)(smem + 2560);     // epilogue: bf16 [512][36] (aliases dead Bs)
    float* Ct = (float*)smem;              // epilogue: [32][520] floats = 66560 B

    const int tid = threadIdx.x, lane = tid & 63, wave = tid >> 6;
    const int wg = blockIdx.x;
    const int s = ((wg & 7) << 7) + (wg >> 3);
    const int m0 = s * 32;
    const int b = m0 >> 12;          // == wg & 7
    const int t0 = m0 & 4095;
    const int hq = wave * 128;       // wave's h-quarter

    floatx4 acc[2][8];
#pragma unroll
    for (int i = 0; i < 2; ++i)
#pragma unroll
        for (int j = 0; j < 8; ++j) acc[i][j] = (floatx4){0.f, 0.f, 0.f, 0.f};

    short8 ra, rb[8];
    const int arow = tid >> 2, acb = (tid & 3) * 8;
    if (tid < 128) ra = *(const short8*)(x_bf + (size_t)(m0 + arow) * INS + acb);
#pragma unroll
    for (int j = 0; j < 8; ++j)
        rb[j] = *(const short8*)(Wt + (size_t)tid * 64 + j * 8);

    for (int c = 0; c < 8; ++c) {
        if (tid < 128) *(short8*)(&As[arow * 40 + acb]) = ra;
#pragma unroll
        for (int j = 0; j < 8; ++j)
            *(short8*)(&Bs[(2 * tid + (j >> 2)) * 40 + (j & 3) * 8]) = rb[j];
        __syncthreads();
        if (c < 7) {
            if (tid < 128) ra = *(const short8*)(x_bf + (size_t)(m0 + arow) * INS + (c + 1) * 32 + acb);
#pragma unroll
            for (int j = 0; j < 8; ++j)
                rb[j] = *(const short8*)(Wt + (size_t)(c + 1) * 16384 + (size_t)tid * 64 + j * 8);
        }
        const int kq = 8 * (lane >> 4);
        const short8 a0 = *(const short8*)(&As[(lane & 15) * 40 + kq]);
        const short8 a1 = *(const short8*)(&As[((lane & 15) + 16) * 40 + kq]);
#pragma unroll
        for (int nf = 0; nf < 8; ++nf) {
            const short8 bv = *(const short8*)(&Bs[(hq + nf * 16 + (lane & 15)) * 40 + kq]);
            acc[0][nf] = __builtin_amdgcn_mfma_f32_16x16x32_bf16(a0, bv, acc[0][nf], 0, 0, 0);
            acc[1][nf] = __builtin_amdgcn_mfma_f32_16x16x32_bf16(a1, bv, acc[1][nf], 0, 0, 0);
        }
        __syncthreads();
    }

    Whbs[tid] = Whb[tid];
    Whbs[tid + 256] = Whb[tid + 256];
#pragma unroll
    for (int i = 0; i < 16; ++i) {
        const int idx = tid + i * 256;          // 0..4095
        const int hh = idx >> 3, tq = (idx & 7) * 4;
        const ush4 v = *(const ush4*)(y + (size_t)(b * HID + hh) * LSEQ + t0 + tq);
        *(ush4*)(&Ys[hh * 36 + tq]) = v;
    }
    __syncthreads();
#pragma unroll
    for (int nf = 0; nf < 8; ++nf) {
        const int hh = hq + nf * 16 + (lane & 15);
        const float bias = Whbs[hh];
#pragma unroll
        for (int mf = 0; mf < 2; ++mf)
#pragma unroll
            for (int r = 0; r < 4; ++r) {
                const int row = mf * 16 + 4 * (lane >> 4) + r;
                acc[mf][nf][r] = fmaxf(acc[mf][nf][r] + bf2f(Ys[hh * 36 + row]) + bias, 0.f);
            }
    }
    __syncthreads();
#pragma unroll
    for (int nf = 0; nf < 8; ++nf) {
        const int col = hq + nf * 16 + (lane & 15);
#pragma unroll
        for (int mf = 0; mf < 2; ++mf)
#pragma unroll
            for (int r = 0; r < 4; ++r) {
                const int row = mf * 16 + 4 * (lane >> 4) + r;
                Ct[row * 520 + col] = acc[mf][nf][r];
            }
    }
    __syncthreads();
#pragma unroll
    for (int i = 0; i < 16; ++i) {
        const int idx = tid + i * 256;          // 0..4095 float4s
        const int row = idx >> 7, c4 = (idx & 127) * 4;
        const floatx4 t = *(const floatx4*)&Ct[row * 520 + c4];
        *(floatx4*)(out + (size_t)(m0 + row) * HID + c4) = t;
        if (((m0 + row) & 4095) == 4095)
            *(floatx4*)(out + (size_t)NB * LSEQ * HID + (size_t)b * HID + c4) = t;
    }
}

extern "C" void kernel_launch(void* const* d_in, const int* in_sizes, int n_in,
                              void* d_out, int out_size, void* d_ws, size_t ws_size,
                              hipStream_t stream) {
    const float* x   = (const float*)d_in[0];
    const float* Wuw = (const float*)d_in[1];
    const float* Wub = (const float*)d_in[2];
    const float* Whw = (const float*)d_in[3];
    const float* Whb = (const float*)d_in[4];
    const float* H   = (const float*)d_in[5];
    char* wsb = (char*)d_ws;
    // workspace layout — byte-identical footprint to the verified round-1 layout
    unsigned short* fftG   = (unsigned short*)(wsb);             // blocked, 33,816,576 B
    unsigned short* yb     = (unsigned short*)(wsb + 33816576);  // 8*512*4096 bf16  = 33,554,432
    float2*         fftU   = (float2*)(wsb + 67371008);          // 32*4128 float2   =  1,056,768
    unsigned short* fftHT  = (unsigned short*)(wsb + 68427776);  // 8256*256 bf16    =  4,227,072
    float*          ut     = (float*)(wsb + 72654848);           // 32*4096 fp32     =    524,288
    unsigned short* x_bf   = (unsigned short*)(wsb + 73179136);  // 32768*256 bf16   = 16,777,216
    unsigned short* Whw_bf = (unsigned short*)(wsb + 89956352);  // [512][1024] bf16 =  1,048,576
    unsigned short* Wt     = (unsigned short*)(wsb + 91004928);  // [8][512][32] bf16=    262,144
    unsigned short* fftHB  = (unsigned short*)(wsb + 91267072);  // 256*8256 bf16    =  4,227,072
    float* out = (float*)d_out;

    hipLaunchKernelGGL(prep_k, dim3(673), dim3(256), 0, stream, Whw, Whw_bf, Wt);
    hipLaunchKernelGGL(stage1_k, dim3(4352), dim3(512), 0, stream, x, Wuw, Wub, ut, x_bf, H, fftHB);
    hipLaunchKernelGGL(stage2_k, dim3(290), dim3(512), 0, stream, ut, fftU, fftHB, fftHT);
    hipLaunchKernelGGL(g_gemm_k, dim3(1040), dim3(256), 0, stream, Whw_bf, fftHT, fftG);
    hipLaunchKernelGGL(conv_ifft_k, dim3(4096), dim3(512), 0, stream, fftU, fftG, yb);
    hipLaunchKernelGGL(out_gemm_k, dim3(1024), dim3(256), 0, stream, x_bf, Wt, Whb, yb, out);
}